// Round 1
// baseline (1935.340 us; speedup 1.0000x reference)
//
#include <hip/hip_runtime.h>

#define HID 128

// ---------------- K1: embedding concat + input MLP (thread = row) ----------------
__global__ __launch_bounds__(64) void k_input(
    const float* __restrict__ xnum, const int* __restrict__ xcat,
    const float* __restrict__ e0, const float* __restrict__ e1,
    const float* __restrict__ e2, const float* __restrict__ e3,
    const float* __restrict__ w, const float* __restrict__ b,
    float* __restrict__ xout, int n)
{
    int row = blockIdx.x * 64 + threadIdx.x;
    if (row >= n) return;
    const float4* xn4 = (const float4*)(xnum + (size_t)row * 32);
    int4 c = ((const int4*)xcat)[row];
    const float* p0 = e0 + (size_t)c.x * 10;
    const float* p1 = e1 + (size_t)c.y * 6;
    const float* p2 = e2 + (size_t)c.z * 5;
    const float* p3 = e3 + (size_t)c.w * 18;
    float* orow = xout + (size_t)row * HID;

    for (int jc = 0; jc < 4; ++jc) {
        const float* wj = w + jc * 32;   // w is (71, 128), uniform index -> s_load
        float acc[32];
        #pragma unroll
        for (int j = 0; j < 32; ++j) acc[j] = b[jc * 32 + j];

        for (int q = 0; q < 8; ++q) {    // x_num: k = 0..31
            float4 v = xn4[q];
            #pragma unroll
            for (int j = 0; j < 32; ++j) acc[j] += v.x * wj[(4 * q + 0) * HID + j];
            #pragma unroll
            for (int j = 0; j < 32; ++j) acc[j] += v.y * wj[(4 * q + 1) * HID + j];
            #pragma unroll
            for (int j = 0; j < 32; ++j) acc[j] += v.z * wj[(4 * q + 2) * HID + j];
            #pragma unroll
            for (int j = 0; j < 32; ++j) acc[j] += v.w * wj[(4 * q + 3) * HID + j];
        }
        for (int k = 0; k < 10; ++k) { float xv = p0[k];
            #pragma unroll
            for (int j = 0; j < 32; ++j) acc[j] += xv * wj[(32 + k) * HID + j]; }
        for (int k = 0; k < 6; ++k) { float xv = p1[k];
            #pragma unroll
            for (int j = 0; j < 32; ++j) acc[j] += xv * wj[(42 + k) * HID + j]; }
        for (int k = 0; k < 5; ++k) { float xv = p2[k];
            #pragma unroll
            for (int j = 0; j < 32; ++j) acc[j] += xv * wj[(48 + k) * HID + j]; }
        for (int k = 0; k < 18; ++k) { float xv = p3[k];
            #pragma unroll
            for (int j = 0; j < 32; ++j) acc[j] += xv * wj[(53 + k) * HID + j]; }

        #pragma unroll
        for (int q = 0; q < 8; ++q) {
            float4 o;
            o.x = fmaxf(acc[4 * q + 0], 0.f);
            o.y = fmaxf(acc[4 * q + 1], 0.f);
            o.z = fmaxf(acc[4 * q + 2], 0.f);
            o.w = fmaxf(acc[4 * q + 3], 0.f);
            ((float4*)(orow + jc * 32))[q] = o;
        }
    }
}

// ---------------- CSR build ----------------
__global__ __launch_bounds__(256) void k_count(const int* __restrict__ dst,
                                               int* __restrict__ cnt, int ecount)
{
    int i = blockIdx.x * blockDim.x + threadIdx.x;
    int stride = gridDim.x * blockDim.x;
    for (; i < ecount; i += stride) atomicAdd(&cnt[dst[i]], 1);
}

__global__ __launch_bounds__(1024) void k_scan1(const int* __restrict__ cnt,
    int* __restrict__ excl, int* __restrict__ bsum, int n)
{
    __shared__ int sm[1024];
    int t = threadIdx.x;
    int base = blockIdx.x * 4096 + t * 4;
    int v0 = (base + 0 < n) ? cnt[base + 0] : 0;
    int v1 = (base + 1 < n) ? cnt[base + 1] : 0;
    int v2 = (base + 2 < n) ? cnt[base + 2] : 0;
    int v3 = (base + 3 < n) ? cnt[base + 3] : 0;
    int s = v0 + v1 + v2 + v3;
    sm[t] = s;
    __syncthreads();
    for (int offd = 1; offd < 1024; offd <<= 1) {
        int tv = (t >= offd) ? sm[t - offd] : 0;
        __syncthreads();
        sm[t] += tv;
        __syncthreads();
    }
    int incl = sm[t];
    int ex = incl - s;
    if (t == 1023) bsum[blockIdx.x] = incl;
    if (base + 0 < n) excl[base + 0] = ex; ex += v0;
    if (base + 1 < n) excl[base + 1] = ex; ex += v1;
    if (base + 2 < n) excl[base + 2] = ex; ex += v2;
    if (base + 3 < n) excl[base + 3] = ex;
}

__global__ void k_scan2(int* __restrict__ bsum, int nb)
{
    if (threadIdx.x == 0 && blockIdx.x == 0) {
        int run = 0;
        for (int i = 0; i < nb; ++i) { int t = bsum[i]; bsum[i] = run; run += t; }
    }
}

__global__ __launch_bounds__(256) void k_scan3(int* __restrict__ row_ptr,
    const int* __restrict__ bsum, int* __restrict__ cursor, int n, int ecount)
{
    int i = blockIdx.x * 256 + threadIdx.x;
    if (i < n) {
        int v = row_ptr[i] + bsum[i >> 12];
        row_ptr[i] = v;
        cursor[i] = v;
    }
    if (i == 0) row_ptr[n] = ecount;
}

__global__ __launch_bounds__(256) void k_fill(const int* __restrict__ src,
    const int* __restrict__ dst, int* __restrict__ cursor,
    int* __restrict__ col, int ecount)
{
    int i = blockIdx.x * blockDim.x + threadIdx.x;
    int stride = gridDim.x * blockDim.x;
    for (; i < ecount; i += stride) {
        int d = dst[i];
        int slot = atomicAdd(&cursor[d], 1);
        col[slot] = src[i];
    }
}

// ---------------- mean aggregation: one wave per node ----------------
__global__ __launch_bounds__(256) void k_agg(const float* __restrict__ x,
    const int* __restrict__ row_ptr, const int* __restrict__ col,
    float* __restrict__ mean, int n)
{
    int lane = threadIdx.x & 63;
    int node = blockIdx.x * 4 + (threadIdx.x >> 6);
    if (node >= n) return;
    node = __builtin_amdgcn_readfirstlane(node);   // force SGPR: scalar row_ptr/col loads
    int s = row_ptr[node];
    int e = row_ptr[node + 1];
    float ax = 0.f, ay = 0.f;
    const float2* x2 = (const float2*)x;
    for (int p = s; p < e; ++p) {
        int sc = col[p];
        float2 v = x2[(size_t)sc * 64 + lane];
        ax += v.x; ay += v.y;
    }
    int deg = e - s;
    float inv = 1.0f / (float)(deg > 1 ? deg : 1);
    float2 o; o.x = ax * inv; o.y = ay * inv;
    ((float2*)mean)[(size_t)node * 64 + lane] = o;
}

// ---------------- fused SAGE linear + LayerNorm + ReLU + residual (thread = row) ----------------
__global__ __launch_bounds__(64) void k_conv(
    const float* __restrict__ mean, float* __restrict__ x,
    const float* __restrict__ wl, const float* __restrict__ bl,
    const float* __restrict__ wr, const float* __restrict__ g,
    const float* __restrict__ be, float* __restrict__ pre, int n)
{
    int row = blockIdx.x * 64 + threadIdx.x;
    if (row >= n) return;
    const float4* m4 = (const float4*)(mean + (size_t)row * HID);
    const float4* x4 = (const float4*)(x + (size_t)row * HID);
    float* prow = pre + (size_t)row * HID;
    float sum = 0.f, ssq = 0.f;

    for (int jc = 0; jc < 4; ++jc) {
        const float* wlj = wl + jc * 32;   // uniform -> s_load
        const float* wrj = wr + jc * 32;
        float acc[32];
        #pragma unroll
        for (int j = 0; j < 32; ++j) acc[j] = bl[jc * 32 + j];

        for (int q = 0; q < 32; ++q) {     // k = 4q .. 4q+3
            float4 mv = m4[q];
            float4 xv = x4[q];
            #pragma unroll
            for (int j = 0; j < 32; ++j)
                acc[j] += mv.x * wlj[(4 * q + 0) * HID + j] + xv.x * wrj[(4 * q + 0) * HID + j];
            #pragma unroll
            for (int j = 0; j < 32; ++j)
                acc[j] += mv.y * wlj[(4 * q + 1) * HID + j] + xv.y * wrj[(4 * q + 1) * HID + j];
            #pragma unroll
            for (int j = 0; j < 32; ++j)
                acc[j] += mv.z * wlj[(4 * q + 2) * HID + j] + xv.z * wrj[(4 * q + 2) * HID + j];
            #pragma unroll
            for (int j = 0; j < 32; ++j)
                acc[j] += mv.w * wlj[(4 * q + 3) * HID + j] + xv.w * wrj[(4 * q + 3) * HID + j];
        }
        #pragma unroll
        for (int j = 0; j < 32; ++j) { sum += acc[j]; ssq += acc[j] * acc[j]; }
        #pragma unroll
        for (int q2 = 0; q2 < 8; ++q2) {
            float4 o;
            o.x = acc[4 * q2 + 0]; o.y = acc[4 * q2 + 1];
            o.z = acc[4 * q2 + 2]; o.w = acc[4 * q2 + 3];
            ((float4*)(prow + jc * 32))[q2] = o;
        }
    }

    float mu = sum * (1.0f / HID);
    float var = ssq * (1.0f / HID) - mu * mu;
    float rs = rsqrtf(var + 1e-5f);
    float* xrow = x + (size_t)row * HID;
    const float4* p4r = (const float4*)prow;
    for (int q = 0; q < 32; ++q) {
        float4 pv = p4r[q];
        float4 xo = ((const float4*)xrow)[q];
        int k0 = 4 * q;
        float4 r;
        r.x = xo.x + 0.5f * fmaxf((pv.x - mu) * rs * g[k0 + 0] + be[k0 + 0], 0.f);
        r.y = xo.y + 0.5f * fmaxf((pv.y - mu) * rs * g[k0 + 1] + be[k0 + 1], 0.f);
        r.z = xo.z + 0.5f * fmaxf((pv.z - mu) * rs * g[k0 + 2] + be[k0 + 2], 0.f);
        r.w = xo.w + 0.5f * fmaxf((pv.w - mu) * rs * g[k0 + 3] + be[k0 + 3], 0.f);
        ((float4*)xrow)[q] = r;
    }
}

// ---------------- head: relu(x@wh1+bh1)@wh2 + bh2 (thread = row) ----------------
__global__ __launch_bounds__(64) void k_head(const float* __restrict__ x,
    const float* __restrict__ wh1, const float* __restrict__ bh1,
    const float* __restrict__ wh2, const float* __restrict__ bh2,
    float* __restrict__ out, int n)
{
    int row = blockIdx.x * 64 + threadIdx.x;
    if (row >= n) return;
    const float4* x4 = (const float4*)(x + (size_t)row * HID);
    float hsum = 0.f;
    for (int jc = 0; jc < 2; ++jc) {
        float acc[32];
        #pragma unroll
        for (int j = 0; j < 32; ++j) acc[j] = bh1[jc * 32 + j];
        for (int q = 0; q < 32; ++q) {
            float4 v = x4[q];
            #pragma unroll
            for (int j = 0; j < 32; ++j) acc[j] += v.x * wh1[(4 * q + 0) * 64 + jc * 32 + j];
            #pragma unroll
            for (int j = 0; j < 32; ++j) acc[j] += v.y * wh1[(4 * q + 1) * 64 + jc * 32 + j];
            #pragma unroll
            for (int j = 0; j < 32; ++j) acc[j] += v.z * wh1[(4 * q + 2) * 64 + jc * 32 + j];
            #pragma unroll
            for (int j = 0; j < 32; ++j) acc[j] += v.w * wh1[(4 * q + 3) * 64 + jc * 32 + j];
        }
        #pragma unroll
        for (int j = 0; j < 32; ++j) hsum += fmaxf(acc[j], 0.f) * wh2[jc * 32 + j];
    }
    out[row] = hsum + bh2[0];
}

// ---------------- launcher ----------------
extern "C" void kernel_launch(void* const* d_in, const int* in_sizes, int n_in,
                              void* d_out, int out_size, void* d_ws, size_t ws_size,
                              hipStream_t stream)
{
    const float* xnum = (const float*)d_in[0];
    const int*   xcat = (const int*)d_in[1];
    const int*   eidx = (const int*)d_in[2];
    const float* e0   = (const float*)d_in[3];
    const float* e1   = (const float*)d_in[4];
    const float* e2   = (const float*)d_in[5];
    const float* e3   = (const float*)d_in[6];
    const float* w_in = (const float*)d_in[7];
    const float* b_in = (const float*)d_in[8];
    const float* w1l  = (const float*)d_in[9];
    const float* b1l  = (const float*)d_in[10];
    const float* w1r  = (const float*)d_in[11];
    const float* w2l  = (const float*)d_in[12];
    const float* b2l  = (const float*)d_in[13];
    const float* w2r  = (const float*)d_in[14];
    const float* g1   = (const float*)d_in[15];
    const float* be1  = (const float*)d_in[16];
    const float* g2   = (const float*)d_in[17];
    const float* be2  = (const float*)d_in[18];
    const float* wh1  = (const float*)d_in[19];
    const float* bh1  = (const float*)d_in[20];
    const float* wh2  = (const float*)d_in[21];
    const float* bh2  = (const float*)d_in[22];

    int n = in_sizes[0] / 32;
    int ecount = in_sizes[2] / 2;
    const int* esrc = eidx;
    const int* edst = eidx + ecount;

    char* ws = (char*)d_ws;
    size_t off = 0;
    auto alloc = [&](size_t bytes) -> void* {
        void* p = ws + off;
        off += (bytes + 255) & ~(size_t)255;
        return p;
    };
    float* xA    = (float*)alloc((size_t)n * HID * 4);
    float* meanB = (float*)alloc((size_t)n * HID * 4);
    float* preB  = (float*)alloc((size_t)n * HID * 4);
    int* cnt     = (int*)alloc((size_t)n * 4);
    int* row_ptr = (int*)alloc((size_t)(n + 1) * 4);
    int* cursor  = (int*)alloc((size_t)n * 4);
    int* col     = (int*)alloc((size_t)ecount * 4);
    int nb1 = (n + 4095) / 4096;
    int* bsum    = (int*)alloc((size_t)nb1 * 4);
    (void)ws_size; (void)n_in; (void)out_size;

    int rowBlocks = (n + 63) / 64;
    int gridE = 2048;

    // input MLP
    k_input<<<rowBlocks, 64, 0, stream>>>(xnum, xcat, e0, e1, e2, e3, w_in, b_in, xA, n);

    // CSR build (by dst)
    hipMemsetAsync(cnt, 0, (size_t)n * 4, stream);
    k_count<<<gridE, 256, 0, stream>>>(edst, cnt, ecount);
    k_scan1<<<nb1, 1024, 0, stream>>>(cnt, row_ptr, bsum, n);
    k_scan2<<<1, 64, 0, stream>>>(bsum, nb1);
    k_scan3<<<(n + 255) / 256, 256, 0, stream>>>(row_ptr, bsum, cursor, n, ecount);
    k_fill<<<gridE, 256, 0, stream>>>(esrc, edst, cursor, col, ecount);

    int aggBlocks = (n + 3) / 4;
    // conv1
    k_agg<<<aggBlocks, 256, 0, stream>>>(xA, row_ptr, col, meanB, n);
    k_conv<<<rowBlocks, 64, 0, stream>>>(meanB, xA, w1l, b1l, w1r, g1, be1, preB, n);
    // conv2
    k_agg<<<aggBlocks, 256, 0, stream>>>(xA, row_ptr, col, meanB, n);
    k_conv<<<rowBlocks, 64, 0, stream>>>(meanB, xA, w2l, b2l, w2r, g2, be2, preB, n);

    // head
    k_head<<<rowBlocks, 64, 0, stream>>>(xA, wh1, bh1, wh2, bh2, (float*)d_out, n);
}

// Round 2
// 1803.918 us; speedup vs baseline: 1.0729x; 1.0729x over previous
//
#include <hip/hip_runtime.h>

#define HID 128

// ---------------- K1: embedding concat + input MLP ----------------
// block = 256 = 4 waves; wave w computes output columns [32w, 32w+32) for 64 rows.
__global__ __launch_bounds__(256) void k_input(
    const float* __restrict__ xnum, const int* __restrict__ xcat,
    const float* __restrict__ e0, const float* __restrict__ e1,
    const float* __restrict__ e2, const float* __restrict__ e3,
    const float* __restrict__ w, const float* __restrict__ b,
    float* __restrict__ xout, int n)
{
    int lane = threadIdx.x & 63;
    int wv   = threadIdx.x >> 6;          // output chunk 0..3
    int row  = blockIdx.x * 64 + lane;
    if (row >= n) return;                 // no barriers in this kernel
    const float4* xn4 = (const float4*)(xnum + (size_t)row * 32);
    int4 c = ((const int4*)xcat)[row];
    const float* p0 = e0 + (size_t)c.x * 10;
    const float* p1 = e1 + (size_t)c.y * 6;
    const float* p2 = e2 + (size_t)c.z * 5;
    const float* p3 = e3 + (size_t)c.w * 18;

    const float* wj = w + wv * 32;        // (71,128), uniform across wave -> s_load
    float acc[32];
    #pragma unroll
    for (int j = 0; j < 32; ++j) acc[j] = b[wv * 32 + j];

    for (int q = 0; q < 8; ++q) {         // x_num: k = 0..31
        float4 v = xn4[q];
        #pragma unroll
        for (int j = 0; j < 32; ++j) acc[j] += v.x * wj[(4 * q + 0) * HID + j];
        #pragma unroll
        for (int j = 0; j < 32; ++j) acc[j] += v.y * wj[(4 * q + 1) * HID + j];
        #pragma unroll
        for (int j = 0; j < 32; ++j) acc[j] += v.z * wj[(4 * q + 2) * HID + j];
        #pragma unroll
        for (int j = 0; j < 32; ++j) acc[j] += v.w * wj[(4 * q + 3) * HID + j];
    }
    for (int k = 0; k < 10; ++k) { float xv = p0[k];
        #pragma unroll
        for (int j = 0; j < 32; ++j) acc[j] += xv * wj[(32 + k) * HID + j]; }
    for (int k = 0; k < 6; ++k) { float xv = p1[k];
        #pragma unroll
        for (int j = 0; j < 32; ++j) acc[j] += xv * wj[(42 + k) * HID + j]; }
    for (int k = 0; k < 5; ++k) { float xv = p2[k];
        #pragma unroll
        for (int j = 0; j < 32; ++j) acc[j] += xv * wj[(48 + k) * HID + j]; }
    for (int k = 0; k < 18; ++k) { float xv = p3[k];
        #pragma unroll
        for (int j = 0; j < 32; ++j) acc[j] += xv * wj[(53 + k) * HID + j]; }

    float* orow = xout + (size_t)row * HID + wv * 32;
    #pragma unroll
    for (int q = 0; q < 8; ++q) {
        float4 o;
        o.x = fmaxf(acc[4 * q + 0], 0.f);
        o.y = fmaxf(acc[4 * q + 1], 0.f);
        o.z = fmaxf(acc[4 * q + 2], 0.f);
        o.w = fmaxf(acc[4 * q + 3], 0.f);
        ((float4*)orow)[q] = o;
    }
}

// ---------------- CSR build ----------------
__global__ __launch_bounds__(256) void k_count(const int* __restrict__ dst,
                                               int* __restrict__ cnt, int ecount)
{
    int i = blockIdx.x * blockDim.x + threadIdx.x;
    int stride = gridDim.x * blockDim.x;
    for (; i < ecount; i += stride) atomicAdd(&cnt[dst[i]], 1);
}

__global__ __launch_bounds__(1024) void k_scan1(const int* __restrict__ cnt,
    int* __restrict__ excl, int* __restrict__ bsum, int n)
{
    __shared__ int sm[1024];
    int t = threadIdx.x;
    int base = blockIdx.x * 4096 + t * 4;
    int v0 = (base + 0 < n) ? cnt[base + 0] : 0;
    int v1 = (base + 1 < n) ? cnt[base + 1] : 0;
    int v2 = (base + 2 < n) ? cnt[base + 2] : 0;
    int v3 = (base + 3 < n) ? cnt[base + 3] : 0;
    int s = v0 + v1 + v2 + v3;
    sm[t] = s;
    __syncthreads();
    for (int offd = 1; offd < 1024; offd <<= 1) {
        int tv = (t >= offd) ? sm[t - offd] : 0;
        __syncthreads();
        sm[t] += tv;
        __syncthreads();
    }
    int incl = sm[t];
    int ex = incl - s;
    if (t == 1023) bsum[blockIdx.x] = incl;
    if (base + 0 < n) excl[base + 0] = ex; ex += v0;
    if (base + 1 < n) excl[base + 1] = ex; ex += v1;
    if (base + 2 < n) excl[base + 2] = ex; ex += v2;
    if (base + 3 < n) excl[base + 3] = ex;
}

__global__ void k_scan2(int* __restrict__ bsum, int nb)
{
    if (threadIdx.x == 0 && blockIdx.x == 0) {
        int run = 0;
        for (int i = 0; i < nb; ++i) { int t = bsum[i]; bsum[i] = run; run += t; }
    }
}

__global__ __launch_bounds__(256) void k_scan3(int* __restrict__ row_ptr,
    const int* __restrict__ bsum, int* __restrict__ cursor, int n, int ecount)
{
    int i = blockIdx.x * 256 + threadIdx.x;
    if (i < n) {
        int v = row_ptr[i] + bsum[i >> 12];
        row_ptr[i] = v;
        cursor[i] = v;
    }
    if (i == 0) row_ptr[n] = ecount;
}

__global__ __launch_bounds__(256) void k_fill(const int* __restrict__ src,
    const int* __restrict__ dst, int* __restrict__ cursor,
    int* __restrict__ col, int ecount)
{
    int i = blockIdx.x * blockDim.x + threadIdx.x;
    int stride = gridDim.x * blockDim.x;
    for (; i < ecount; i += stride) {
        int d = dst[i];
        int slot = atomicAdd(&cursor[d], 1);
        col[slot] = src[i];
    }
}

// ---------------- mean aggregation: one wave per node ----------------
__global__ __launch_bounds__(256) void k_agg(const float* __restrict__ x,
    const int* __restrict__ row_ptr, const int* __restrict__ col,
    float* __restrict__ mean, int n)
{
    int lane = threadIdx.x & 63;
    int node = blockIdx.x * 4 + (threadIdx.x >> 6);
    if (node >= n) return;
    node = __builtin_amdgcn_readfirstlane(node);   // force SGPR: scalar row_ptr/col loads
    int s = row_ptr[node];
    int e = row_ptr[node + 1];
    float ax = 0.f, ay = 0.f;
    const float2* x2 = (const float2*)x;
    for (int p = s; p < e; ++p) {
        int sc = col[p];
        float2 v = x2[(size_t)sc * 64 + lane];
        ax += v.x; ay += v.y;
    }
    int deg = e - s;
    float inv = 1.0f / (float)(deg > 1 ? deg : 1);
    float2 o; o.x = ax * inv; o.y = ay * inv;
    ((float2*)mean)[(size_t)node * 64 + lane] = o;
}

// ---------------- fused SAGE linear + LayerNorm + ReLU + residual ----------------
// block = 256 = 4 waves; wave w owns output columns [32w,32w+32) for 64 rows.
// LN mean/var via 4-way cross-wave LDS reduction; acc stays in registers (no `pre`).
__global__ __launch_bounds__(256) void k_conv(
    const float* __restrict__ mean, float* __restrict__ x,
    const float* __restrict__ wl, const float* __restrict__ bl,
    const float* __restrict__ wr, const float* __restrict__ g,
    const float* __restrict__ be, int n)
{
    __shared__ float sSum[4][64];
    __shared__ float sSsq[4][64];
    int lane = threadIdx.x & 63;
    int wv   = threadIdx.x >> 6;
    int row  = blockIdx.x * 64 + lane;
    int rl   = row < n ? row : n - 1;     // clamp: keep loads in-bounds, all threads reach barrier
    const float4* m4 = (const float4*)(mean + (size_t)rl * HID);
    const float4* x4 = (const float4*)(x + (size_t)rl * HID);
    const float* wlj = wl + wv * 32;      // uniform -> s_load
    const float* wrj = wr + wv * 32;

    float acc[32];
    #pragma unroll
    for (int j = 0; j < 32; ++j) acc[j] = bl[wv * 32 + j];

    for (int q = 0; q < 32; ++q) {        // k = 4q .. 4q+3
        float4 mv = m4[q];
        float4 xv = x4[q];
        #pragma unroll
        for (int j = 0; j < 32; ++j)
            acc[j] += mv.x * wlj[(4 * q + 0) * HID + j] + xv.x * wrj[(4 * q + 0) * HID + j];
        #pragma unroll
        for (int j = 0; j < 32; ++j)
            acc[j] += mv.y * wlj[(4 * q + 1) * HID + j] + xv.y * wrj[(4 * q + 1) * HID + j];
        #pragma unroll
        for (int j = 0; j < 32; ++j)
            acc[j] += mv.z * wlj[(4 * q + 2) * HID + j] + xv.z * wrj[(4 * q + 2) * HID + j];
        #pragma unroll
        for (int j = 0; j < 32; ++j)
            acc[j] += mv.w * wlj[(4 * q + 3) * HID + j] + xv.w * wrj[(4 * q + 3) * HID + j];
    }

    float s = 0.f, ss = 0.f;
    #pragma unroll
    for (int j = 0; j < 32; ++j) { s += acc[j]; ss += acc[j] * acc[j]; }
    sSum[wv][lane] = s;
    sSsq[wv][lane] = ss;
    __syncthreads();
    float sum = sSum[0][lane] + sSum[1][lane] + sSum[2][lane] + sSum[3][lane];
    float ssq = sSsq[0][lane] + sSsq[1][lane] + sSsq[2][lane] + sSsq[3][lane];
    float mu  = sum * (1.0f / HID);
    float var = ssq * (1.0f / HID) - mu * mu;
    float rs  = rsqrtf(var + 1e-5f);

    if (row < n) {
        float* xrow = x + (size_t)row * HID + wv * 32;
        #pragma unroll
        for (int q2 = 0; q2 < 8; ++q2) {
            float4 xo = ((const float4*)xrow)[q2];
            int k0 = wv * 32 + 4 * q2;
            float4 r;
            r.x = xo.x + 0.5f * fmaxf((acc[4 * q2 + 0] - mu) * rs * g[k0 + 0] + be[k0 + 0], 0.f);
            r.y = xo.y + 0.5f * fmaxf((acc[4 * q2 + 1] - mu) * rs * g[k0 + 1] + be[k0 + 1], 0.f);
            r.z = xo.z + 0.5f * fmaxf((acc[4 * q2 + 2] - mu) * rs * g[k0 + 2] + be[k0 + 2], 0.f);
            r.w = xo.w + 0.5f * fmaxf((acc[4 * q2 + 3] - mu) * rs * g[k0 + 3] + be[k0 + 3], 0.f);
            ((float4*)xrow)[q2] = r;
        }
    }
}

// ---------------- head: relu(x@wh1+bh1)@wh2 + bh2 ----------------
// block = 128 = 2 waves; wave w owns hidden columns [32w,32w+32).
__global__ __launch_bounds__(128) void k_head(const float* __restrict__ x,
    const float* __restrict__ wh1, const float* __restrict__ bh1,
    const float* __restrict__ wh2, const float* __restrict__ bh2,
    float* __restrict__ out, int n)
{
    __shared__ float sP[2][64];
    int lane = threadIdx.x & 63;
    int wv   = threadIdx.x >> 6;
    int row  = blockIdx.x * 64 + lane;
    int rl   = row < n ? row : n - 1;
    const float4* x4 = (const float4*)(x + (size_t)rl * HID);

    float acc[32];
    #pragma unroll
    for (int j = 0; j < 32; ++j) acc[j] = bh1[wv * 32 + j];
    for (int q = 0; q < 32; ++q) {
        float4 v = x4[q];
        #pragma unroll
        for (int j = 0; j < 32; ++j) acc[j] += v.x * wh1[(4 * q + 0) * 64 + wv * 32 + j];
        #pragma unroll
        for (int j = 0; j < 32; ++j) acc[j] += v.y * wh1[(4 * q + 1) * 64 + wv * 32 + j];
        #pragma unroll
        for (int j = 0; j < 32; ++j) acc[j] += v.z * wh1[(4 * q + 2) * 64 + wv * 32 + j];
        #pragma unroll
        for (int j = 0; j < 32; ++j) acc[j] += v.w * wh1[(4 * q + 3) * 64 + wv * 32 + j];
    }
    float part = 0.f;
    #pragma unroll
    for (int j = 0; j < 32; ++j) part += fmaxf(acc[j], 0.f) * wh2[wv * 32 + j];
    sP[wv][lane] = part;
    __syncthreads();
    if (wv == 0 && row < n)
        out[row] = sP[0][lane] + sP[1][lane] + bh2[0];
}

// ---------------- launcher ----------------
extern "C" void kernel_launch(void* const* d_in, const int* in_sizes, int n_in,
                              void* d_out, int out_size, void* d_ws, size_t ws_size,
                              hipStream_t stream)
{
    const float* xnum = (const float*)d_in[0];
    const int*   xcat = (const int*)d_in[1];
    const int*   eidx = (const int*)d_in[2];
    const float* e0   = (const float*)d_in[3];
    const float* e1   = (const float*)d_in[4];
    const float* e2   = (const float*)d_in[5];
    const float* e3   = (const float*)d_in[6];
    const float* w_in = (const float*)d_in[7];
    const float* b_in = (const float*)d_in[8];
    const float* w1l  = (const float*)d_in[9];
    const float* b1l  = (const float*)d_in[10];
    const float* w1r  = (const float*)d_in[11];
    const float* w2l  = (const float*)d_in[12];
    const float* b2l  = (const float*)d_in[13];
    const float* w2r  = (const float*)d_in[14];
    const float* g1   = (const float*)d_in[15];
    const float* be1  = (const float*)d_in[16];
    const float* g2   = (const float*)d_in[17];
    const float* be2  = (const float*)d_in[18];
    const float* wh1  = (const float*)d_in[19];
    const float* bh1  = (const float*)d_in[20];
    const float* wh2  = (const float*)d_in[21];
    const float* bh2  = (const float*)d_in[22];

    int n = in_sizes[0] / 32;
    int ecount = in_sizes[2] / 2;
    const int* esrc = eidx;
    const int* edst = eidx + ecount;

    char* ws = (char*)d_ws;
    size_t off = 0;
    auto alloc = [&](size_t bytes) -> void* {
        void* p = ws + off;
        off += (bytes + 255) & ~(size_t)255;
        return p;
    };
    float* xA    = (float*)alloc((size_t)n * HID * 4);
    float* meanB = (float*)alloc((size_t)n * HID * 4);
    int* cnt     = (int*)alloc((size_t)n * 4);
    int* row_ptr = (int*)alloc((size_t)(n + 1) * 4);
    int* cursor  = (int*)alloc((size_t)n * 4);
    int* col     = (int*)alloc((size_t)ecount * 4);
    int nb1 = (n + 4095) / 4096;
    int* bsum    = (int*)alloc((size_t)nb1 * 4);
    (void)ws_size; (void)n_in; (void)out_size;

    int rowBlocks = (n + 63) / 64;
    int gridE = 2048;

    // input MLP
    k_input<<<rowBlocks, 256, 0, stream>>>(xnum, xcat, e0, e1, e2, e3, w_in, b_in, xA, n);

    // CSR build (by dst)
    hipMemsetAsync(cnt, 0, (size_t)n * 4, stream);
    k_count<<<gridE, 256, 0, stream>>>(edst, cnt, ecount);
    k_scan1<<<nb1, 1024, 0, stream>>>(cnt, row_ptr, bsum, n);
    k_scan2<<<1, 64, 0, stream>>>(bsum, nb1);
    k_scan3<<<(n + 255) / 256, 256, 0, stream>>>(row_ptr, bsum, cursor, n, ecount);
    k_fill<<<gridE, 256, 0, stream>>>(esrc, edst, cursor, col, ecount);

    int aggBlocks = (n + 3) / 4;
    // conv1
    k_agg<<<aggBlocks, 256, 0, stream>>>(xA, row_ptr, col, meanB, n);
    k_conv<<<rowBlocks, 256, 0, stream>>>(meanB, xA, w1l, b1l, w1r, g1, be1, n);
    // conv2
    k_agg<<<aggBlocks, 256, 0, stream>>>(xA, row_ptr, col, meanB, n);
    k_conv<<<rowBlocks, 256, 0, stream>>>(meanB, xA, w2l, b2l, w2r, g2, be2, n);

    // head
    k_head<<<rowBlocks, 128, 0, stream>>>(xA, wh1, bh1, wh2, bh2, (float*)d_out, n);
}

// Round 4
// 944.073 us; speedup vs baseline: 2.0500x; 1.9108x over previous
//
#include <hip/hip_runtime.h>

#define HID 128

typedef __attribute__((ext_vector_type(8))) short short8;
typedef __attribute__((ext_vector_type(4))) float f32x4;

__device__ __forceinline__ float bf2f(unsigned short u) {
    unsigned int x = ((unsigned int)u) << 16;
    return __builtin_bit_cast(float, x);
}
__device__ __forceinline__ unsigned short f2bf(float f) {
    unsigned int u = __builtin_bit_cast(unsigned int, f);
    u += 0x7fffu + ((u >> 16) & 1u);
    return (unsigned short)(u >> 16);
}

// ---------------- weight prep: fp32 [K,N] (optionally two stacked sources) ->
// fragment layout hi/lo: elem (k,n) at ((k/32)*N + n)*32 + k%32 ----------------
__global__ __launch_bounds__(256) void k_prepw(const float* __restrict__ s1, int k1,
    const float* __restrict__ s2, int k2, int Kp, int N,
    unsigned short* __restrict__ whi, unsigned short* __restrict__ wlo)
{
    int i = blockIdx.x * 256 + threadIdx.x;
    if (i >= Kp * N) return;
    int k = i / N, nn = i - k * N;
    float v = 0.f;
    if (k < k1) v = s1[(size_t)k * N + nn];
    else if (k < k1 + k2) v = s2[(size_t)(k - k1) * N + nn];
    unsigned short h = f2bf(v);
    unsigned short l = f2bf(v - bf2f(h));
    size_t o = ((size_t)(k >> 5) * N + nn) * 32 + (k & 31);
    whi[o] = h; wlo[o] = l;
}

// ---------------- input feature prestack: [xnum | emb0..3 | pad] -> bf16 hi/lo pairs,
// A0 row-major [n][192] = [hi(96) | lo(96)].  6 chunks of 16 cols per row. ----------------
__global__ __launch_bounds__(256) void k_stack0(
    const float* __restrict__ xnum, const int* __restrict__ xcat,
    const float* __restrict__ e0, const float* __restrict__ e1,
    const float* __restrict__ e2, const float* __restrict__ e3,
    unsigned short* __restrict__ A0, int n)
{
    int g = blockIdx.x * 256 + threadIdx.x;
    int r = g / 6, c = g - r * 6;              // 6 chunks of 16 cols (96 features)
    if (r >= n) return;
    int4 cc = ((const int4*)xcat)[r];
    float v[16];
    int base = c * 16;
    #pragma unroll
    for (int j = 0; j < 16; ++j) {
        int col = base + j;
        float val;
        if      (col < 32) val = xnum[(size_t)r * 32 + col];
        else if (col < 42) val = e0[(size_t)cc.x * 10 + (col - 32)];
        else if (col < 48) val = e1[(size_t)cc.y * 6  + (col - 42)];
        else if (col < 53) val = e2[(size_t)cc.z * 5  + (col - 48)];
        else if (col < 71) val = e3[(size_t)cc.w * 18 + (col - 53)];
        else               val = 0.f;
        v[j] = val;
    }
    unsigned int ph[8], pl[8];
    #pragma unroll
    for (int j = 0; j < 8; ++j) {
        unsigned short h0 = f2bf(v[2*j]),   h1 = f2bf(v[2*j+1]);
        unsigned short l0 = f2bf(v[2*j]   - bf2f(h0));
        unsigned short l1 = f2bf(v[2*j+1] - bf2f(h1));
        ph[j] = (unsigned int)h0 | ((unsigned int)h1 << 16);
        pl[j] = (unsigned int)l0 | ((unsigned int)l1 << 16);
    }
    unsigned int* dh = (unsigned int*)(A0 + (size_t)r * 192 + base);
    unsigned int* dl = (unsigned int*)(A0 + (size_t)r * 192 + 96 + base);
    uint4 a; a.x = ph[0]; a.y = ph[1]; a.z = ph[2]; a.w = ph[3];
    uint4 b; b.x = ph[4]; b.y = ph[5]; b.z = ph[6]; b.w = ph[7];
    ((uint4*)dh)[0] = a; ((uint4*)dh)[1] = b;
    a.x = pl[0]; a.y = pl[1]; a.z = pl[2]; a.w = pl[3];
    b.x = pl[4]; b.y = pl[5]; b.z = pl[6]; b.w = pl[7];
    ((uint4*)dl)[0] = a; ((uint4*)dl)[1] = b;
}

// ---------------- CSR build ----------------
__global__ __launch_bounds__(256) void k_count(const int* __restrict__ dst,
                                               int* __restrict__ cnt, int ecount)
{
    int i = blockIdx.x * blockDim.x + threadIdx.x;
    int stride = gridDim.x * blockDim.x;
    for (; i < ecount; i += stride) atomicAdd(&cnt[dst[i]], 1);
}

__global__ __launch_bounds__(1024) void k_scan1(const int* __restrict__ cnt,
    int* __restrict__ excl, int* __restrict__ bsum, int n)
{
    __shared__ int sm[1024];
    int t = threadIdx.x;
    int base = blockIdx.x * 4096 + t * 4;
    int v0 = (base + 0 < n) ? cnt[base + 0] : 0;
    int v1 = (base + 1 < n) ? cnt[base + 1] : 0;
    int v2 = (base + 2 < n) ? cnt[base + 2] : 0;
    int v3 = (base + 3 < n) ? cnt[base + 3] : 0;
    int s = v0 + v1 + v2 + v3;
    sm[t] = s;
    __syncthreads();
    for (int offd = 1; offd < 1024; offd <<= 1) {
        int tv = (t >= offd) ? sm[t - offd] : 0;
        __syncthreads();
        sm[t] += tv;
        __syncthreads();
    }
    int incl = sm[t];
    int ex = incl - s;
    if (t == 1023) bsum[blockIdx.x] = incl;
    if (base + 0 < n) excl[base + 0] = ex; ex += v0;
    if (base + 1 < n) excl[base + 1] = ex; ex += v1;
    if (base + 2 < n) excl[base + 2] = ex; ex += v2;
    if (base + 3 < n) excl[base + 3] = ex;
}

__global__ void k_scan2(int* __restrict__ bsum, int nb)
{
    if (threadIdx.x == 0 && blockIdx.x == 0) {
        int run = 0;
        for (int i = 0; i < nb; ++i) { int t = bsum[i]; bsum[i] = run; run += t; }
    }
}

__global__ __launch_bounds__(256) void k_scan3(int* __restrict__ row_ptr,
    const int* __restrict__ bsum, int* __restrict__ cursor, int n, int ecount)
{
    int i = blockIdx.x * 256 + threadIdx.x;
    if (i < n) {
        int v = row_ptr[i] + bsum[i >> 12];
        row_ptr[i] = v;
        cursor[i] = v;
    }
    if (i == 0) row_ptr[n] = ecount;
}

__global__ __launch_bounds__(256) void k_fill(const int* __restrict__ src,
    const int* __restrict__ dst, int* __restrict__ cursor,
    int* __restrict__ col, int ecount)
{
    int i = blockIdx.x * blockDim.x + threadIdx.x;
    int stride = gridDim.x * blockDim.x;
    for (; i < ecount; i += stride) {
        int d = dst[i];
        int slot = atomicAdd(&cursor[d], 1);
        col[slot] = src[i];
    }
}

// ---------------- mean aggregation over bf16 pairs: one wave per node ----------------
__global__ __launch_bounds__(256) void k_agg(
    const unsigned short* __restrict__ xh, const unsigned short* __restrict__ xl,
    unsigned short* __restrict__ mh, unsigned short* __restrict__ ml, int SK,
    const int* __restrict__ row_ptr, const int* __restrict__ col, int n)
{
    int lane = threadIdx.x & 63;
    int node = blockIdx.x * 4 + (threadIdx.x >> 6);
    if (node >= n) return;
    node = __builtin_amdgcn_readfirstlane(node);
    int s = row_ptr[node], e = row_ptr[node + 1];
    int c2 = lane * 2;                 // two columns per lane
    float a0 = 0.f, a1 = 0.f;
    for (int p = s; p < e; ++p) {
        int sc = col[p];
        size_t o = (size_t)sc * SK + c2;
        unsigned int hh = *(const unsigned int*)(xh + o);
        unsigned int ll = *(const unsigned int*)(xl + o);
        a0 += __builtin_bit_cast(float, hh << 16) + __builtin_bit_cast(float, ll << 16);
        a1 += __builtin_bit_cast(float, hh & 0xffff0000u) + __builtin_bit_cast(float, ll & 0xffff0000u);
    }
    int deg = e - s;
    float inv = 1.f / (float)(deg > 1 ? deg : 1);
    a0 *= inv; a1 *= inv;
    unsigned short h0 = f2bf(a0), h1 = f2bf(a1);
    unsigned short l0 = f2bf(a0 - bf2f(h0)), l1 = f2bf(a1 - bf2f(h1));
    size_t o = (size_t)node * SK + c2;
    *(unsigned int*)(mh + o) = (unsigned int)h0 | ((unsigned int)h1 << 16);
    *(unsigned int*)(ml + o) = (unsigned int)l0 | ((unsigned int)l1 << 16);
}

// ---------------- generic split-bf16 MFMA GEMM, M-tile=64, block=256 ----------------
// A' row-major [m][SK], SK = 2*KT8*32 = [hi-half | lo-half].
// K-schedule (3*KT8 steps): (A_hi,W_hi), (A_lo,W_hi), (A_hi,W_lo).
// EPI 0: out = relu(C+bias) -> pair store.  EPI 1: LN+relu, out = res + 0.5*r -> pair store.
// EPI 2: head: s = relu(C+bias)·wh2 + bh2 -> outp.
template<int NC, int EPI>
__global__ __launch_bounds__(256) void k_gemm(
    const unsigned short* __restrict__ A, int SK, int KT8,
    const unsigned short* __restrict__ Whi, const unsigned short* __restrict__ Wlo,
    const float* __restrict__ bias,
    const float* __restrict__ g, const float* __restrict__ be,
    const unsigned short* __restrict__ SrcH, const unsigned short* __restrict__ SrcL, int SSK,
    unsigned short* __restrict__ DstH, unsigned short* __restrict__ DstL, int DSK,
    const float* __restrict__ wh2, const float* __restrict__ bh2, float* __restrict__ outp,
    int n)
{
    constexpr int NT = NC / 64;       // n-16-tiles per wave
    constexpr int CW = NC / 4;        // epilogue cols per thread
    __shared__ float Cb[64][NC + 4];
    int t = threadIdx.x;
    int lane = t & 63, w = t >> 6;
    int l15 = lane & 15, kg = lane >> 4;
    int m0 = blockIdx.x * 64;

    size_t aoff[4];
    #pragma unroll
    for (int mt = 0; mt < 4; ++mt) {
        int r = m0 + mt * 16 + l15;
        r = r < n ? r : n - 1;
        aoff[mt] = (size_t)r * SK + kg * 8;
    }
    size_t nb[NT];
    #pragma unroll
    for (int nt = 0; nt < NT; ++nt)
        nb[nt] = (size_t)(w * (NC / 4) + nt * 16 + l15) * 32 + kg * 8;

    f32x4 acc[4][NT];
    #pragma unroll
    for (int mt = 0; mt < 4; ++mt)
        #pragma unroll
        for (int nt = 0; nt < NT; ++nt)
            acc[mt][nt] = (f32x4)(0.f);

    int steps = 3 * KT8;
    for (int s = 0; s < steps; ++s) {
        int at = (s < 2 * KT8) ? s : s - 2 * KT8;
        int wt = (s >= 2 * KT8) ? (s - 2 * KT8) : ((s >= KT8) ? s - KT8 : s);
        const unsigned short* Wp = (s >= 2 * KT8) ? Wlo : Whi;
        int koff = at * 32;
        short8 af[4];
        #pragma unroll
        for (int mt = 0; mt < 4; ++mt)
            af[mt] = *(const short8*)(A + aoff[mt] + koff);
        short8 bfr[NT];
        #pragma unroll
        for (int nt = 0; nt < NT; ++nt)
            bfr[nt] = *(const short8*)(Wp + (size_t)wt * NC * 32 + nb[nt]);
        #pragma unroll
        for (int mt = 0; mt < 4; ++mt)
            #pragma unroll
            for (int nt = 0; nt < NT; ++nt)
                acc[mt][nt] = __builtin_amdgcn_mfma_f32_16x16x32_bf16(af[mt], bfr[nt], acc[mt][nt], 0, 0, 0);
    }

    // acc -> LDS Cbuf  (C/D layout: col = lane&15, row = quad*4 + reg)
    #pragma unroll
    for (int mt = 0; mt < 4; ++mt)
        #pragma unroll
        for (int nt = 0; nt < NT; ++nt)
            #pragma unroll
            for (int r = 0; r < 4; ++r)
                Cb[mt * 16 + kg * 4 + r][w * (NC / 4) + nt * 16 + l15] = acc[mt][nt][r];
    __syncthreads();

    int er = t >> 2, q = t & 3;
    int gr = m0 + er;
    int cb = q * CW;

    if (EPI == 0) {
        if (gr < n) {
            #pragma unroll
            for (int i = 0; i < CW / 4; ++i) {
                int c = cb + 4 * i;
                float4 v  = *(const float4*)&Cb[er][c];
                float4 bi = *(const float4*)&bias[c];
                float o0 = fmaxf(v.x + bi.x, 0.f), o1 = fmaxf(v.y + bi.y, 0.f);
                float o2 = fmaxf(v.z + bi.z, 0.f), o3 = fmaxf(v.w + bi.w, 0.f);
                unsigned short h0 = f2bf(o0), h1 = f2bf(o1), h2 = f2bf(o2), h3 = f2bf(o3);
                ushort4 hv = make_ushort4(h0, h1, h2, h3);
                ushort4 lv = make_ushort4(f2bf(o0 - bf2f(h0)), f2bf(o1 - bf2f(h1)),
                                          f2bf(o2 - bf2f(h2)), f2bf(o3 - bf2f(h3)));
                *(ushort4*)(DstH + (size_t)gr * DSK + c) = hv;
                *(ushort4*)(DstL + (size_t)gr * DSK + c) = lv;
            }
        }
    } else if (EPI == 1) {
        float s = 0.f, ss = 0.f;
        #pragma unroll
        for (int i = 0; i < CW / 4; ++i) {
            int c = cb + 4 * i;
            float4 v  = *(const float4*)&Cb[er][c];
            float4 bi = *(const float4*)&bias[c];
            float a0 = v.x + bi.x, a1 = v.y + bi.y, a2 = v.z + bi.z, a3 = v.w + bi.w;
            s  += a0 + a1 + a2 + a3;
            ss += a0 * a0 + a1 * a1 + a2 * a2 + a3 * a3;
        }
        s  += __shfl_xor(s, 1);  s  += __shfl_xor(s, 2);
        ss += __shfl_xor(ss, 1); ss += __shfl_xor(ss, 2);
        float mu  = s * (1.f / NC);
        float var = ss * (1.f / NC) - mu * mu;
        float rs  = rsqrtf(var + 1e-5f);
        if (gr < n) {
            #pragma unroll
            for (int i = 0; i < CW / 4; ++i) {
                int c = cb + 4 * i;
                float4 v  = *(const float4*)&Cb[er][c];
                float4 bi = *(const float4*)&bias[c];
                float4 gg = *(const float4*)&g[c];
                float4 bb = *(const float4*)&be[c];
                float r0 = fmaxf((v.x + bi.x - mu) * rs * gg.x + bb.x, 0.f);
                float r1 = fmaxf((v.y + bi.y - mu) * rs * gg.y + bb.y, 0.f);
                float r2 = fmaxf((v.z + bi.z - mu) * rs * gg.z + bb.z, 0.f);
                float r3 = fmaxf((v.w + bi.w - mu) * rs * gg.w + bb.w, 0.f);
                ushort4 rh = *(const ushort4*)(SrcH + (size_t)gr * SSK + c);
                ushort4 rl = *(const ushort4*)(SrcL + (size_t)gr * SSK + c);
                float o0 = bf2f(rh.x) + bf2f(rl.x) + 0.5f * r0;
                float o1 = bf2f(rh.y) + bf2f(rl.y) + 0.5f * r1;
                float o2 = bf2f(rh.z) + bf2f(rl.z) + 0.5f * r2;
                float o3 = bf2f(rh.w) + bf2f(rl.w) + 0.5f * r3;
                unsigned short h0 = f2bf(o0), h1 = f2bf(o1), h2 = f2bf(o2), h3 = f2bf(o3);
                ushort4 hv = make_ushort4(h0, h1, h2, h3);
                ushort4 lv = make_ushort4(f2bf(o0 - bf2f(h0)), f2bf(o1 - bf2f(h1)),
                                          f2bf(o2 - bf2f(h2)), f2bf(o3 - bf2f(h3)));
                *(ushort4*)(DstH + (size_t)gr * DSK + c) = hv;
                *(ushort4*)(DstL + (size_t)gr * DSK + c) = lv;
            }
        }
    } else {
        float s = 0.f;
        #pragma unroll
        for (int i = 0; i < CW / 4; ++i) {
            int c = cb + 4 * i;
            float4 v  = *(const float4*)&Cb[er][c];
            float4 bi = *(const float4*)&bias[c];
            float4 w2 = *(const float4*)&wh2[c];
            s += fmaxf(v.x + bi.x, 0.f) * w2.x + fmaxf(v.y + bi.y, 0.f) * w2.y
               + fmaxf(v.z + bi.z, 0.f) * w2.z + fmaxf(v.w + bi.w, 0.f) * w2.w;
        }
        s += __shfl_xor(s, 1); s += __shfl_xor(s, 2);
        if (q == 0 && gr < n) outp[gr] = s + bh2[0];
    }
}

// ---------------- launcher ----------------
extern "C" void kernel_launch(void* const* d_in, const int* in_sizes, int n_in,
                              void* d_out, int out_size, void* d_ws, size_t ws_size,
                              hipStream_t stream)
{
    const float* xnum = (const float*)d_in[0];
    const int*   xcat = (const int*)d_in[1];
    const int*   eidx = (const int*)d_in[2];
    const float* e0   = (const float*)d_in[3];
    const float* e1   = (const float*)d_in[4];
    const float* e2   = (const float*)d_in[5];
    const float* e3   = (const float*)d_in[6];
    const float* w_in = (const float*)d_in[7];
    const float* b_in = (const float*)d_in[8];
    const float* w1l  = (const float*)d_in[9];
    const float* b1l  = (const float*)d_in[10];
    const float* w1r  = (const float*)d_in[11];
    const float* w2l  = (const float*)d_in[12];
    const float* b2l  = (const float*)d_in[13];
    const float* w2r  = (const float*)d_in[14];
    const float* g1   = (const float*)d_in[15];
    const float* be1  = (const float*)d_in[16];
    const float* g2   = (const float*)d_in[17];
    const float* be2  = (const float*)d_in[18];
    const float* wh1  = (const float*)d_in[19];
    const float* bh1  = (const float*)d_in[20];
    const float* wh2  = (const float*)d_in[21];
    const float* bh2  = (const float*)d_in[22];

    int n = in_sizes[0] / 32;
    int ecount = in_sizes[2] / 2;
    const int* esrc = eidx;
    const int* edst = eidx + ecount;

    char* ws = (char*)d_ws;
    size_t off = 0;
    auto alloc = [&](size_t bytes) -> void* {
        void* p = ws + off;
        off += (bytes + 255) & ~(size_t)255;
        return p;
    };
    // Region R0: A1 (n x 512 pairs) ; A3 (n x 256) aliases it (A1 dead after conv1).
    unsigned short* A1 = (unsigned short*)alloc((size_t)n * 512 * 2);
    unsigned short* A3 = A1;
    // Region R1: A2 (n x 512) ; A0 (n x 192) aliases it (A0 dead before conv1 epilogue writes A2).
    unsigned short* A2 = (unsigned short*)alloc((size_t)n * 512 * 2);
    unsigned short* A0 = A2;
    // Weight fragment buffers
    unsigned short* w0h = (unsigned short*)alloc((size_t)96 * 128 * 2);
    unsigned short* w0l = (unsigned short*)alloc((size_t)96 * 128 * 2);
    unsigned short* w1h = (unsigned short*)alloc((size_t)256 * 128 * 2);
    unsigned short* w1lo= (unsigned short*)alloc((size_t)256 * 128 * 2);
    unsigned short* w2h = (unsigned short*)alloc((size_t)256 * 128 * 2);
    unsigned short* w2lo= (unsigned short*)alloc((size_t)256 * 128 * 2);
    unsigned short* whh = (unsigned short*)alloc((size_t)128 * 64 * 2);
    unsigned short* whl = (unsigned short*)alloc((size_t)128 * 64 * 2);
    // CSR
    int* cnt     = (int*)alloc((size_t)n * 4);
    int* row_ptr = (int*)alloc((size_t)(n + 1) * 4);
    int* cursor  = (int*)alloc((size_t)n * 4);
    int* col     = (int*)alloc((size_t)ecount * 4);
    int nb1 = (n + 4095) / 4096;
    int* bsum    = (int*)alloc((size_t)nb1 * 4);
    (void)ws_size; (void)n_in; (void)out_size;

    int gemmBlocks = (n + 63) / 64;
    int gridE = 2048;
    int aggBlocks = (n + 3) / 4;

    // weight prep
    k_prepw<<<(96 * 128 + 255) / 256, 256, 0, stream>>>(w_in, 71, nullptr, 0, 96, 128, w0h, w0l);
    k_prepw<<<(256 * 128 + 255) / 256, 256, 0, stream>>>(w1l, 128, w1r, 128, 256, 128, w1h, w1lo);
    k_prepw<<<(256 * 128 + 255) / 256, 256, 0, stream>>>(w2l, 128, w2r, 128, 256, 128, w2h, w2lo);
    k_prepw<<<(128 * 64 + 255) / 256, 256, 0, stream>>>(wh1, 128, nullptr, 0, 128, 64, whh, whl);

    // input features -> A0
    k_stack0<<<((size_t)n * 6 + 255) / 256, 256, 0, stream>>>(xnum, xcat, e0, e1, e2, e3, A0, n);

    // CSR build (by dst)
    hipMemsetAsync(cnt, 0, (size_t)n * 4, stream);
    k_count<<<gridE, 256, 0, stream>>>(edst, cnt, ecount);
    k_scan1<<<nb1, 1024, 0, stream>>>(cnt, row_ptr, bsum, n);
    k_scan2<<<1, 64, 0, stream>>>(bsum, nb1);
    k_scan3<<<(n + 255) / 256, 256, 0, stream>>>(row_ptr, bsum, cursor, n, ecount);
    k_fill<<<gridE, 256, 0, stream>>>(esrc, edst, cursor, col, ecount);

    // input MLP: A0[192] @ W0 -> x0 pairs into A1 x-slots (hi@128, lo@384)
    k_gemm<128, 0><<<gemmBlocks, 256, 0, stream>>>(
        A0, 192, 3, w0h, w0l, b_in,
        nullptr, nullptr, nullptr, nullptr, 0,
        A1 + 128, A1 + 384, 512,
        nullptr, nullptr, nullptr, n);

    // conv1: mean of x0 -> A1 mean-slots; GEMM A1[512] @ [w1l;w1r] -> x1 pairs -> A2 x-slots
    k_agg<<<aggBlocks, 256, 0, stream>>>(A1 + 128, A1 + 384, A1, A1 + 256, 512, row_ptr, col, n);
    k_gemm<128, 1><<<gemmBlocks, 256, 0, stream>>>(
        A1, 512, 8, w1h, w1lo, b1l,
        g1, be1, A1 + 128, A1 + 384, 512,
        A2 + 128, A2 + 384, 512,
        nullptr, nullptr, nullptr, n);

    // conv2: mean of x1 -> A2 mean-slots; GEMM A2[512] -> x2 pairs -> A3 (hi@0, lo@128)
    k_agg<<<aggBlocks, 256, 0, stream>>>(A2 + 128, A2 + 384, A2, A2 + 256, 512, row_ptr, col, n);
    k_gemm<128, 1><<<gemmBlocks, 256, 0, stream>>>(
        A2, 512, 8, w2h, w2lo, b2l,
        g2, be2, A2 + 128, A2 + 384, 512,
        A3, A3 + 128, 256,
        nullptr, nullptr, nullptr, n);

    // head: A3[256] @ wh1 -> relu -> ·wh2 + bh2 -> out
    k_gemm<64, 2><<<gemmBlocks, 256, 0, stream>>>(
        A3, 256, 4, whh, whl, bh1,
        nullptr, nullptr, nullptr, nullptr, 0,
        nullptr, nullptr, 0,
        wh2, bh2, (float*)d_out, n);
}